// Round 13
// baseline (204.543 us; speedup 1.0000x reference)
//
#include <hip/hip_runtime.h>
#include <cstdint>

constexpr int N_FEAT  = 8;
constexpr int E_FEAT  = 4;
constexpr int NUM_IN  = 2 * (N_FEAT + 2) + E_FEAT + 1;  // 25
constexpr int NUM_OUT = 2 * N_FEAT + E_FEAT;            // 20
constexpr int BLK     = 256;   // 4 waves; 256 edges per block
constexpr int RS      = 40;    // LDS row stride in halves = 80 B = 20 fp32

// BARRIER-FREE MFMA kernel. Session evidence: R6/R10/R11/R12 all ~64-70us
// at ~2.1 TB/s with VALU<=15%, MFMA 2.4%, occupancy 35-47%; R9 proved 74%
// occupancy alone doesn't lift BW. Remaining suspect: __syncthreads after
// weight staging gang-idles all waves -> CU load-issue duty cycle ~10-40%.
// This version removes ALL synchronization:
//  - sX is wave-partitioned (wave w touches only rows [64w,64w+64)); the
//    per-wave in-order DS pipe orders write->read without any barrier.
//  - Weight fragments (the only shared data) load DIRECTLY from global into
//    per-lane registers (8 guarded dwords per fragment, 4 fragments; L2/L3
//    resident after the first blocks). sW/staging/barrier deleted.
// LDS 25->20.5 KB (7 blocks/CU headroom); every wave is an independent
// gather->MFMA->store pipeline, so some wave is always issuing loads.

typedef _Float16 f16x8 __attribute__((ext_vector_type(8)));
typedef float    f32x4 __attribute__((ext_vector_type(4)));

// Guarded per-lane fragment load: rows>=nrow or cols>=ncol -> 0 (zero-pad).
__device__ __forceinline__ f16x8 load_frag(const float* __restrict__ W,
                                           int row, int col0, int nrow, int ncol) {
  f16x8 f = (f16x8)(_Float16)0.f;
  if (row < nrow) {
    const float* wr = W + row * ncol + col0;
#pragma unroll
    for (int i = 0; i < 8; ++i)
      if (col0 + i < ncol) f[i] = (_Float16)wr[i];
  }
  return f;
}

__global__ __launch_bounds__(BLK)
__attribute__((amdgpu_waves_per_eu(4, 8)))
void edge_mlp(
    const float* __restrict__ r,
    const float* __restrict__ a_data,
    const float* __restrict__ a_mat,
    const float* __restrict__ a_inf,
    const float* __restrict__ b_data,
    const float* __restrict__ b_mat,
    const float* __restrict__ b_inf,
    const float* __restrict__ e_data,
    const float* __restrict__ W1,   // (25,25) row-major fp32
    const float* __restrict__ B1,   // (25,)
    const float* __restrict__ W2,   // (20,25) row-major
    const float* __restrict__ B2,   // (20,)
    float*       __restrict__ out,  // fp32, 3 segments concatenated
    int E) {
  __shared__ __align__(16) _Float16 sX[BLK * RS];   // 20.5 KB; X -> H -> y(fp32)

  const int tid  = threadIdx.x;
  const int lane = tid & 63;
  const int lr   = lane & 15;          // fragment row (A) / col (B,C)
  const int lk   = (lane >> 4) * 8;    // k-octet base
  const int rg   = (lane >> 4) * 4;    // C/D row-group base
  const int wid  = tid >> 6;

  // ---- gather this thread's edge (proven coalesced float4 path) -> fp16 ----
  const int ebase = blockIdx.x * BLK;
  int eg = ebase + tid;
  if (eg >= E) eg = E - 1;          // clamp for loads; stores are guarded
  const float4* a4 = reinterpret_cast<const float4*>(a_data) + 2 * (size_t)eg;
  const float4* b4 = reinterpret_cast<const float4*>(b_data) + 2 * (size_t)eg;
  const float4 a0 = a4[0], a1 = a4[1];
  const float4 b0 = b4[0], b1v = b4[1];
  const float4 ev = reinterpret_cast<const float4*>(e_data)[eg];
  const float rv = r[eg], am = a_mat[eg], ai = a_inf[eg];
  const float bm = b_mat[eg], bi = b_inf[eg];

  // ---- per-lane weight fragments + biases straight from global (L2-hit) ----
  const f16x8 w1a = load_frag(W1, lr,      lk, NUM_IN,  NUM_IN);
  const f16x8 w1b = load_frag(W1, 16 + lr, lk, NUM_IN,  NUM_IN);
  const f16x8 w2a = load_frag(W2, lr,      lk, NUM_OUT, NUM_IN);
  const f16x8 w2b = load_frag(W2, 16 + lr, lk, NUM_OUT, NUM_IN);
  const float b1a = B1[lr];
  const float b1b = (16 + lr < NUM_IN) ? B1[16 + lr] : 0.f;
  const float b2a = B2[lr];                                  // lr<16<20: valid
  const float b2b = (16 + lr < NUM_OUT) ? B2[16 + lr] : 0.f;

  // ---- pack X row to fp16 and write to this wave's sX partition ----
  f16x8 p0, p1, p2, p3;
  p0[0] = (_Float16)rv;    p0[1] = (_Float16)a0.x;  p0[2] = (_Float16)a0.y;
  p0[3] = (_Float16)a0.z;  p0[4] = (_Float16)a0.w;  p0[5] = (_Float16)a1.x;
  p0[6] = (_Float16)a1.y;  p0[7] = (_Float16)a1.z;
  p1[0] = (_Float16)a1.w;  p1[1] = (_Float16)am;    p1[2] = (_Float16)ai;
  p1[3] = (_Float16)b0.x;  p1[4] = (_Float16)b0.y;  p1[5] = (_Float16)b0.z;
  p1[6] = (_Float16)b0.w;  p1[7] = (_Float16)b1v.x;
  p2[0] = (_Float16)b1v.y; p2[1] = (_Float16)b1v.z; p2[2] = (_Float16)b1v.w;
  p2[3] = (_Float16)bm;    p2[4] = (_Float16)bi;    p2[5] = (_Float16)ev.x;
  p2[6] = (_Float16)ev.y;  p2[7] = (_Float16)ev.z;
  p3 = (f16x8)(_Float16)0.f;
  p3[0] = (_Float16)ev.w;

  _Float16* xrow = &sX[tid * RS];
  *reinterpret_cast<f16x8*>(xrow + 0)  = p0;
  *reinterpret_cast<f16x8*>(xrow + 8)  = p1;
  *reinterpret_cast<f16x8*>(xrow + 16) = p2;
  *reinterpret_cast<f16x8*>(xrow + 24) = p3;

  // NO __syncthreads: all sX rows this wave reads ([wid*64, wid*64+64)) were
  // written by this wave's own lanes; per-wave DS ops complete in order.

  float* sY = reinterpret_cast<float*>(sX);   // row stride 20 fp32 (= 80 B)

#pragma unroll
  for (int t = 0; t < 4; ++t) {
    const int rb = wid * 64 + t * 16;   // tile's row base within block

    // ---- layer 1: C = X @ W1^T + b1 ----
    const f16x8 xa = *reinterpret_cast<const f16x8*>(&sX[(rb + lr) * RS + lk]);
    f32x4 c0 = {b1a, b1a, b1a, b1a};
    f32x4 c1 = {b1b, b1b, b1b, b1b};
    c0 = __builtin_amdgcn_mfma_f32_16x16x32_f16(xa, w1a, c0, 0, 0, 0);
    c1 = __builtin_amdgcn_mfma_f32_16x16x32_f16(xa, w1b, c1, 0, 0, 0);

    // ---- relu -> fp16 -> in-place over this tile's dead X rows ----
#pragma unroll
    for (int q = 0; q < 4; ++q) {
      const int hr = rb + rg + q;
      sX[hr * RS + lr]      = (_Float16)fmaxf(c0[q], 0.f);
      sX[hr * RS + 16 + lr] = (_Float16)fmaxf(c1[q], 0.f);
    }

    // ---- layer 2: D = H @ W2^T + b2 (same-wave in-order DS) ----
    const f16x8 ha = *reinterpret_cast<const f16x8*>(&sX[(rb + lr) * RS + lk]);
    f32x4 d0 = {b2a, b2a, b2a, b2a};
    f32x4 d1 = {b2b, b2b, b2b, b2b};
    d0 = __builtin_amdgcn_mfma_f32_16x16x32_f16(ha, w2a, d0, 0, 0, 0);
    d1 = __builtin_amdgcn_mfma_f32_16x16x32_f16(ha, w2b, d1, 0, 0, 0);

    // ---- relu -> y staged in LDS as fp32 over this tile's dead rows ----
#pragma unroll
    for (int q = 0; q < 4; ++q) {
      const int yr = rb + rg + q;
      sY[yr * 20 + lr] = fmaxf(d0[q], 0.f);                    // cols 0..15
      if (lr < 4) sY[yr * 20 + 16 + lr] = fmaxf(d1[q], 0.f);   // cols 16..19
    }
  }

  // ---- each thread stores its own edge: 5 x float4 (proven coalesced path) ----
  const int e0 = ebase + tid;
  if (e0 < E) {
    const float* yr = sY + tid * 20;
    const float4 v0 = *reinterpret_cast<const float4*>(yr + 0);
    const float4 v1 = *reinterpret_cast<const float4*>(yr + 4);
    const float4 v2 = *reinterpret_cast<const float4*>(yr + 8);
    const float4 v3 = *reinterpret_cast<const float4*>(yr + 12);
    const float4 v4 = *reinterpret_cast<const float4*>(yr + 16);
    float4* o0 = reinterpret_cast<float4*>(out) + 2 * (size_t)e0;           // (E,8)
    o0[0] = v0;
    o0[1] = v1;
    float4* o1 = reinterpret_cast<float4*>(out + (size_t)8 * E) + 2 * (size_t)e0;  // (E,8)
    o1[0] = v2;
    o1[1] = v3;
    reinterpret_cast<float4*>(out + (size_t)16 * E)[e0] = v4;               // (E,4)
  }
}

extern "C" void kernel_launch(void* const* d_in, const int* in_sizes, int n_in,
                              void* d_out, int out_size, void* d_ws, size_t ws_size,
                              hipStream_t stream) {
  const float* r      = (const float*)d_in[0];
  const float* a_data = (const float*)d_in[1];
  const float* a_mat  = (const float*)d_in[2];
  const float* a_inf  = (const float*)d_in[3];
  const float* b_data = (const float*)d_in[4];
  const float* b_mat  = (const float*)d_in[5];
  const float* b_inf  = (const float*)d_in[6];
  const float* e_data = (const float*)d_in[7];
  const float* W1     = (const float*)d_in[8];
  const float* B1     = (const float*)d_in[9];
  const float* W2     = (const float*)d_in[10];
  const float* B2     = (const float*)d_in[11];
  int E = in_sizes[0];

  edge_mlp<<<(E + BLK - 1) / BLK, BLK, 0, stream>>>(
      r, a_data, a_mat, a_inf, b_data, b_mat, b_inf, e_data,
      W1, B1, W2, B2, (float*)d_out, E);
}